// Round 7
// baseline (963.879 us; speedup 1.0000x reference)
//
#include <hip/hip_runtime.h>
#include <stdint.h>
#include <math.h>

// Bit-exact canonical-f32 sparse fold (validated rounds 4-6, absmax 0.0):
// y[r][j] = ascending-k f32 FMA fold over nonzero masked weights, + bias,
// * boost, exact radix top-k on f32 t-bits, keep ties (>=).
//
// Round 7: attack latency, not issue count. R6 showed VGPR_Count=56 (default
// 8-waves/EU budget) strangled the fold into dependent load->lds->fma batches
// (VALU 27%, LDS ~45%, HBM 23% -- nothing saturated). Fix:
//   __launch_bounds__(256,3) -> ~170 VGPR budget, explicit e+1 prefetch of all
//   16 pair regs while FMAing e. 16-way MLP on both L2 and LDS paths.
// Select phase unchanged (isolate the variable).

#define BATCH 16384
#define K_DIM 512
#define N_DIM 4096
#define RPB 4
#define MAXE 64

typedef float f32x4 __attribute__((ext_vector_type(4)));
typedef unsigned int u32;

// ---------- boost table ----------
__global__ void boost_kernel(const float* __restrict__ duty,
                             const int* __restrict__ kptr,
                             float* __restrict__ boost) {
  const int j = blockIdx.x * blockDim.x + threadIdx.x;
  if (j < N_DIM) {
    const float td = (float)((double)kptr[0] / (double)N_DIM);
    const float arg = 0.5f * (td - duty[j]);      // f32 ops, as reference
    boost[j] = (float)exp((double)arg);           // correctly-rounded f32 exp
  }
}

// ---------- compress: per-column nonzeros, ascending k ----------
__global__ __launch_bounds__(256) void compress_kernel(
    const float* __restrict__ W, const float* __restrict__ mask,
    unsigned short* __restrict__ cIdx, float* __restrict__ cVal,
    int* __restrict__ cnt) {
  const int j = blockIdx.x * 4 + (threadIdx.x >> 6);  // one wave per column
  const int lane = threadIdx.x & 63;
  if (j >= N_DIM) return;
  const float* mr = mask + (size_t)j * K_DIM;
  const float* wr = W + (size_t)j * K_DIM;
  int base = 0;
#pragma unroll
  for (int c = 0; c < K_DIM / 64; ++c) {
    const int k = c * 64 + lane;
    const bool act = (mr[k] != 0.0f);
    const unsigned long long bal = __ballot(act);
    const int pos = __popcll(bal & ((1ull << lane) - 1ull));
    if (act && base + pos < MAXE) {
      cIdx[(size_t)j * MAXE + base + pos] = (unsigned short)k;
      cVal[(size_t)j * MAXE + base + pos] = wr[k];   // mask==1 -> exact
    }
    base += (int)__popcll(bal);
  }
  if (lane == 0) cnt[j] = base < MAXE ? base : MAXE;
}

// ---------- counting sort of columns by nnz; per-thread loop bounds ----------
__global__ __launch_bounds__(256) void sort_kernel(
    const int* __restrict__ cnt, int* __restrict__ perm, int* __restrict__ tE) {
  __shared__ int hist[MAXE + 1];
  __shared__ int off[MAXE + 1];
  const int tid = threadIdx.x;
  if (tid <= MAXE) hist[tid] = 0;
  __syncthreads();
  for (int j = tid; j < N_DIM; j += 256) atomicAdd(&hist[cnt[j]], 1);
  __syncthreads();
  if (tid == 0) {
    int s = 0;
    for (int c = 0; c <= MAXE; ++c) { off[c] = s; s += hist[c]; }
  }
  __syncthreads();
  for (int j = tid; j < N_DIM; j += 256) {
    const int p = atomicAdd(&off[cnt[j]], 1);
    perm[p] = j;                                   // ascending count
  }
  __syncthreads();
  // thread t owns sorted ranks [t*16, t*16+16); max count = last rank's count
  tE[tid] = cnt[perm[tid * 16 + 15]];
}

// ---------- fill transposed padded pair array in slot order ----------
__global__ __launch_bounds__(256) void fill_kernel(
    const unsigned short* __restrict__ cIdx, const float* __restrict__ cVal,
    const int* __restrict__ cnt, const int* __restrict__ perm,
    uint2* __restrict__ pairT, int* __restrict__ orig) {
  const int s = blockIdx.x * 256 + threadIdx.x;    // sorted rank 0..4095
  const int j = perm[s];
  const int c = cnt[j];
  const int slot = (s & 15) * 256 + (s >> 4);      // u*256 + tid
  orig[slot] = j;
#pragma unroll 4
  for (int e = 0; e < MAXE; ++e) {
    uint2 pr;
    if (e < c) {
      pr.x = (u32)cIdx[(size_t)j * MAXE + e] * 16u; // LDS byte offset (k*16)
      pr.y = __float_as_uint(cVal[(size_t)j * MAXE + e]);
    } else {
      pr.x = 0u; pr.y = 0u;                         // fmaf(0,..) no-op
    }
    pairT[(size_t)e * N_DIM + slot] = pr;
  }
}

// ---------- fused gather-GEMM + exact top-k select ----------
__global__ __launch_bounds__(256, 3) void fused_kernel(
    const float* __restrict__ x, const float* __restrict__ bvec,
    const uint2* __restrict__ pairT, const float* __restrict__ boost,
    const int* __restrict__ orig, const int* __restrict__ tE,
    const int* __restrict__ kptr, float* __restrict__ out) {
  // smem: x tile [512][4] (8 KB) during fold; one y row [4096] (16 KB) after
  __shared__ __align__(16) float smem[N_DIM];
  __shared__ u32 hist[256];
  __shared__ u32 s_prefix, s_kk;

  const int tid = threadIdx.x;
  const int row0 = blockIdx.x * RPB;

  // stage RPB rows of x: smem[k*4 + r]
  for (int i = tid; i < K_DIM; i += 256)
#pragma unroll
    for (int r = 0; r < RPB; ++r)
      smem[i * 4 + r] = x[(size_t)(row0 + r) * K_DIM + i];

  const int myE = tE[tid];
  const int kk0 = kptr[0];
  float a[RPB][16];
#pragma unroll
  for (int r = 0; r < RPB; ++r)
#pragma unroll
    for (int u = 0; u < 16; ++u) a[r][u] = 0.0f;
  __syncthreads();

  // gather fold with explicit e+1 prefetch: 16-way MLP on L2 and LDS paths
  uint2 prc[16];
  if (myE > 0) {
    const uint2* p0 = pairT + tid;
#pragma unroll
    for (int u = 0; u < 16; ++u) prc[u] = p0[u * 256];
  }
  for (int e = 0; e < myE; ++e) {
    uint2 prn[16];
    const bool more = (e + 1 < myE);
    const uint2* pn = pairT + (size_t)(e + 1) * N_DIM + tid;
#pragma unroll
    for (int u = 0; u < 16; ++u)
      if (more) prn[u] = pn[u * 256];               // prefetch next e
#pragma unroll
    for (int u = 0; u < 16; ++u) {
      const f32x4 xs = *(const f32x4*)((const char*)smem + prc[u].x);
      const float w = __uint_as_float(prc[u].y);
      a[0][u] = fmaf(w, xs[0], a[0][u]);
      a[1][u] = fmaf(w, xs[1], a[1][u]);
      a[2][u] = fmaf(w, xs[2], a[2][u]);
      a[3][u] = fmaf(w, xs[3], a[3][u]);
    }
#pragma unroll
    for (int u = 0; u < 16; ++u)
      if (more) prc[u] = prn[u];
  }

  // per row: re-permute to original order via LDS, bias+boost, select, store
#pragma unroll 1
  for (int r = 0; r < RPB; ++r) {
    __syncthreads();                                // smem free; s_* free
#pragma unroll
    for (int u = 0; u < 16; ++u)
      smem[orig[u * 256 + tid]] = a[r][u];          // scatter to orig col
    if (tid == 0) { s_prefix = 0u; s_kk = (u32)kk0; }
    __syncthreads();

    float y[16], bl[16];
    u32 key[16];
#pragma unroll
    for (int u = 0; u < 16; ++u) {
      const int j = u * 256 + tid;
      y[u] = smem[j] + bvec[j];                     // single f32 add
      bl[u] = boost[j];
      const float t = y[u] * bl[u];                 // single f32 mult
      const u32 v = __float_as_uint(t);
      key[u] = (v & 0x80000000u) ? ~v : (v | 0x80000000u);
    }

#pragma unroll 1
    for (int round = 0; round < 4; ++round) {
      const int shift = 24 - 8 * round;
      const u32 prefix = s_prefix;
      const u32 kk = s_kk;
      const u32 himask = round ? (0xFFFFFFFFu << (32 - 8 * round)) : 0u;
      hist[tid] = 0u;
      __syncthreads();
#pragma unroll
      for (int u = 0; u < 16; ++u)
        if ((key[u] & himask) == prefix)
          atomicAdd(&hist[(key[u] >> shift) & 255u], 1u);
      __syncthreads();
      if (tid < 64) {                               // wave 0: suffix scan
        const int l = tid;
        const u32 h0 = hist[l * 4], h1 = hist[l * 4 + 1];
        const u32 h2 = hist[l * 4 + 2], h3 = hist[l * 4 + 3];
        const u32 s3 = h3, s2 = h2 + s3, s1 = h1 + s2, s0 = h0 + s1;
        u32 t = s0;
#pragma unroll
        for (int off = 1; off < 64; off <<= 1) {
          const u32 v = __shfl_down(t, off, 64);
          if (l + off < 64) t += v;
        }
        const u32 Eab = t - s0;                     // lanes strictly above
        const u32 S[5] = {Eab + s0, Eab + s1, Eab + s2, Eab + s3, Eab};
#pragma unroll
        for (int i = 0; i < 4; ++i)
          if (S[i] >= kk && S[i + 1] < kk) {
            s_prefix = prefix | ((u32)(l * 4 + i) << shift);
            s_kk = kk - S[i + 1];
          }
      }
      __syncthreads();
    }
    const u32 tkey = s_prefix;

    float* orow = out + (size_t)(row0 + r) * N_DIM;
#pragma unroll
    for (int u = 0; u < 16; ++u)
      orow[u * 256 + tid] = (key[u] >= tkey) ? y[u] : 0.0f;
  }
}

extern "C" void kernel_launch(void* const* d_in, const int* in_sizes, int n_in,
                              void* d_out, int out_size, void* d_ws, size_t ws_size,
                              hipStream_t stream) {
  const float* x     = (const float*)d_in[0];
  const float* W     = (const float*)d_in[1];
  const float* bvec  = (const float*)d_in[2];
  const float* wmask = (const float*)d_in[3];
  const float* duty  = (const float*)d_in[4];
  const int* kptr    = (const int*)d_in[5];
  float* out = (float*)d_out;

  uint8_t* ws = (uint8_t*)d_ws;
  unsigned short* cIdx = (unsigned short*)(ws);                 // 512 KiB
  float* cVal          = (float*)(ws + (1u << 20));             // 1 MiB
  int* cnt             = (int*)(ws + (2u << 20));               // 16 KiB
  float* boost         = (float*)(ws + (2u << 20) + (64u << 10));
  int* perm            = (int*)(ws + (2u << 20) + (128u << 10)); // 16 KiB
  int* tE              = (int*)(ws + (2u << 20) + (192u << 10)); // 1 KiB
  int* orig            = (int*)(ws + (2u << 20) + (256u << 10)); // 16 KiB
  uint2* pairT         = (uint2*)(ws + (4u << 20));             // 2 MiB

  boost_kernel<<<16, 256, 0, stream>>>(duty, kptr, boost);
  compress_kernel<<<N_DIM / 4, 256, 0, stream>>>(W, wmask, cIdx, cVal, cnt);
  sort_kernel<<<1, 256, 0, stream>>>(cnt, perm, tE);
  fill_kernel<<<N_DIM / 256, 256, 0, stream>>>(cIdx, cVal, cnt, perm, pairT, orig);
  fused_kernel<<<BATCH / RPB, 256, 0, stream>>>(x, bvec, pairT, boost, orig, tE,
                                                kptr, out);
}